// Round 3
// baseline (522.220 us; speedup 1.0000x reference)
//
#include <hip/hip_runtime.h>
#include <hip/hip_fp16.h>
#include <math.h>

typedef _Float16 half_t;
typedef __attribute__((ext_vector_type(8))) _Float16 half8;
typedef __attribute__((ext_vector_type(4))) float f32x4;

#define AS1 __attribute__((address_space(1)))
#define AS3 __attribute__((address_space(3)))

#define N_ROWS 8192
#define DFULL 768
#define LOG2E 1.4426950408889634f
#define KSC (LOG2E / 0.05f)
#define NEGSH (-28.853900817779268f)   // -20 * log2(e)
#define LN2 0.6931471805599453f

__device__ __forceinline__ void gload_lds16(const void* g, void* l) {
  __builtin_amdgcn_global_load_lds((const AS1 void*)g, (AS3 void*)l, 16, 0, 0);
}

// ---------------- kernel 1: per-row prefix norms + fp16 convert ----------------
__global__ __launch_bounds__(256) void mcl_prep(
    const float* __restrict__ e1, const float* __restrict__ e2,
    half_t* __restrict__ h1, half_t* __restrict__ h2,
    float* __restrict__ inv1, float* __restrict__ inv2)
{
  const int b = blockIdx.x;
  const int mat = b >> 13, row = b & (N_ROWS - 1);
  const float* src = (mat ? e2 : e1) + (size_t)row * DFULL;
  half_t* dst = (mat ? h2 : h1) + (size_t)row * DFULL;
  float* invo = mat ? inv2 : inv1;
  const int t = threadIdx.x;

  float p0=0.f,p1=0.f,p2=0.f,p3=0.f,p4=0.f;
#pragma unroll
  for (int j = 0; j < 3; ++j) {
    const int e = t + j * 256;
    const float x = src[e];
    dst[e] = (half_t)x;
    const float xx = x * x;
    p0 += (e < 64)  ? xx : 0.f;
    p1 += (e < 128) ? xx : 0.f;
    p2 += (e < 256) ? xx : 0.f;
    p3 += (e < 512) ? xx : 0.f;
    p4 += xx;
  }
#pragma unroll
  for (int off = 32; off > 0; off >>= 1) {
    p0 += __shfl_down(p0, off, 64);
    p1 += __shfl_down(p1, off, 64);
    p2 += __shfl_down(p2, off, 64);
    p3 += __shfl_down(p3, off, 64);
    p4 += __shfl_down(p4, off, 64);
  }
  __shared__ float red[4][5];
  const int lane = t & 63, w = t >> 6;
  if (lane == 0) { red[w][0]=p0; red[w][1]=p1; red[w][2]=p2; red[w][3]=p3; red[w][4]=p4; }
  __syncthreads();
  if (t == 0) {
#pragma unroll
    for (int s = 0; s < 5; ++s) {
      const float q = red[0][s]+red[1][s]+red[2][s]+red[3][s];
      invo[s * N_ROWS + row] = 1.f / fmaxf(sqrtf(q), 1e-8f);
    }
  }
}

// ---------------- kernel 2: fused cumulative GEMM + checkpoint softmax partials ----------------
// 512 threads = 8 waves (2 row-groups x 4 col-groups); per-wave output 64x32.
// Swapped-operand MFMA: acc[n][m] = mfma(bf[n], af[m], .) ->
//   i (softmax row)  = wr*64 + m*16 + (lane&15)        [lane-low]
//   j (reduce axis)  = wc*32 + n*16 + (lane>>4)*4 + rg [register + lane-hi]
// Double-buffered LDS staging, one barrier per K-chunk, setprio around MFMA.
__global__ __launch_bounds__(512, 2) void mcl_main(
    const half_t* __restrict__ h1, const half_t* __restrict__ h2,
    const float* __restrict__ inv1, const float* __restrict__ inv2,
    float* __restrict__ diag, float* __restrict__ partial)
{
  __shared__ __align__(16) half_t sA[2][128 * 64];
  __shared__ __align__(16) half_t sB[2][128 * 64];
  __shared__ float rowsumW[4][5][128];   // [wc][dim][row]
  __shared__ float inv1s[5][128];
  __shared__ float inv2s[5][128];

  const int tid = threadIdx.x;
  const int lane = tid & 63, wid = tid >> 6;      // wid 0..7
  const int wr = wid >> 2, wc = wid & 3;          // 2 x 4 wave grid
  const int l15 = lane & 15, lh = lane >> 4;

  // XCD-chunked + 8x8-supertile swizzle (bijective: 4096 = 8 * 512)
  const int id = blockIdx.x;
  const int nid = (id & 7) * 512 + (id >> 3);
  const int st = nid >> 6, tt = nid & 63;
  const int bi = ((st >> 3) << 3) + (tt >> 3);
  const int bj = ((st & 7) << 3) + (tt & 7);
  const int rowA0 = bi * 128, rowB0 = bj * 128;

  for (int x = tid; x < 4 * 5 * 128; x += 512) ((float*)rowsumW)[x] = 0.f;
  for (int x = tid; x < 5 * 128; x += 512) {
    const int d = x >> 7, r = x & 127;
    inv1s[d][r] = inv1[d * N_ROWS + rowA0 + r];
    inv2s[d][r] = inv2[d * N_ROWS + rowB0 + r];
  }

  f32x4 acc[2][4];  // [n][m]
#pragma unroll
  for (int n = 0; n < 2; ++n)
#pragma unroll
    for (int m = 0; m < 4; ++m) acc[n][m] = (f32x4)0.f;

  // ---- staging (linear LDS dest; XOR swizzle pre-applied to global src) ----
#define STAGE(buf, k0_)                                                        \
  {                                                                            \
    const int k0s = (k0_);                                                     \
    _Pragma("unroll")                                                          \
    for (int r = 0; r < 2; ++r) {                                              \
      const int c = ((r * 8 + wid) << 6) + lane;                               \
      const int row = c >> 3, slot = c & 7;                                    \
      const int koff = k0s + ((slot ^ (row & 7)) << 3);                        \
      gload_lds16(h1 + (size_t)(rowA0 + row) * DFULL + koff,                   \
                  (char*)&sA[buf][0] + ((size_t)(r * 8 + wid) << 10));         \
      gload_lds16(h2 + (size_t)(rowB0 + row) * DFULL + koff,                   \
                  (char*)&sB[buf][0] + ((size_t)(r * 8 + wid) << 10));         \
    }                                                                          \
  }

  STAGE(0, 0);
  __syncthreads();

  int dcp = 0;
#pragma unroll 2
  for (int ck = 0; ck < 12; ++ck) {
    const int cur = ck & 1;
    if (ck < 11) STAGE(cur ^ 1, (ck + 1) * 64);

    const half_t* sAc = &sA[cur][0];
    const half_t* sBc = &sB[cur][0];
    // ---- 2 MFMA K-steps of 32 ----
#pragma unroll
    for (int ks = 0; ks < 2; ++ks) {
      half8 af[4], bf[2];
#pragma unroll
      for (int m = 0; m < 4; ++m) {
        const int rowa = wr * 64 + m * 16 + l15;
        const int slota = (ks * 4 + lh) ^ (rowa & 7);
        af[m] = *(const half8*)((const char*)sAc + rowa * 128 + (slota << 4));
      }
#pragma unroll
      for (int n = 0; n < 2; ++n) {
        const int rowb = wc * 32 + n * 16 + l15;
        const int slotb = (ks * 4 + lh) ^ (rowb & 7);
        bf[n] = *(const half8*)((const char*)sBc + rowb * 128 + (slotb << 4));
      }
      __builtin_amdgcn_s_setprio(1);
#pragma unroll
      for (int n = 0; n < 2; ++n)
#pragma unroll
        for (int m = 0; m < 4; ++m)
          acc[n][m] = __builtin_amdgcn_mfma_f32_16x16x32_f16(bf[n], af[m], acc[n][m], 0, 0, 0);
      __builtin_amdgcn_s_setprio(0);
    }
    // ---- checkpoint epilogue (cumulative K = 64,128,256,512,768) ----
    if (ck == 0 || ck == 1 || ck == 3 || ck == 7 || ck == 11) {
      float s1K[4];
#pragma unroll
      for (int m = 0; m < 4; ++m)
        s1K[m] = inv1s[dcp][wr * 64 + m * 16 + l15] * KSC;
      float s2v[2][4];
#pragma unroll
      for (int n = 0; n < 2; ++n)
#pragma unroll
        for (int rg = 0; rg < 4; ++rg)
          s2v[n][rg] = inv2s[dcp][wc * 32 + n * 16 + (lh << 2) + rg];

      float rp[4] = {0.f, 0.f, 0.f, 0.f};
#pragma unroll
      for (int n = 0; n < 2; ++n)
#pragma unroll
        for (int m = 0; m < 4; ++m)
#pragma unroll
          for (int rg = 0; rg < 4; ++rg)
            rp[m] += __builtin_amdgcn_exp2f(fmaf(acc[n][m][rg] * s2v[n][rg], s1K[m], NEGSH));

      // reduce over lane-hi (j sub-axis)
#pragma unroll
      for (int m = 0; m < 4; ++m) {
        rp[m] += __shfl_xor(rp[m], 16, 64);
        rp[m] += __shfl_xor(rp[m], 32, 64);
      }
      if (lh == 0) {
#pragma unroll
        for (int m = 0; m < 4; ++m)
          rowsumW[wc][dcp][wr * 64 + m * 16 + l15] += rp[m];
      }
      // diagonal logits: i==j needs (wc>>1)==wr, m=((wc&1)<<1)+n, lh*4+rg==l15
      if (bi == bj && (wc >> 1) == wr && lh == (l15 >> 2)) {
        const int rgd = l15 & 3;
#pragma unroll
        for (int n = 0; n < 2; ++n) {
          const int m = ((wc & 1) << 1) + n;
          const float lg = acc[n][m][rgd] * s1K[m] * s2v[n][rgd] * LN2;
          diag[dcp * N_ROWS + rowA0 + wr * 64 + m * 16 + l15] = lg;
        }
      }
      ++dcp;
    }
    __syncthreads();
  }
#undef STAGE

  // write per-(column-block) partial sumexp
  for (int x = tid; x < 5 * 128; x += 512) {
    const int d = x >> 7, r = x & 127;
    partial[((size_t)bj * 5 + d) * N_ROWS + rowA0 + r] =
        rowsumW[0][d][r] + rowsumW[1][d][r] + rowsumW[2][d][r] + rowsumW[3][d][r];
  }
}

// ---------------- kernel 3: final reduction ----------------
__global__ __launch_bounds__(256) void mcl_reduce(
    const float* __restrict__ partial, const float* __restrict__ diag,
    float* __restrict__ out)
{
  const int item = blockIdx.x * 256 + threadIdx.x;  // 0..40959
  const int d = item >> 13;
  const int i = item & (N_ROWS - 1);
  float s = 0.f;
#pragma unroll 4
  for (int bj = 0; bj < 64; ++bj)
    s += partial[((size_t)bj * 5 + d) * N_ROWS + i];
  float term = (20.0f + logf(s) - diag[d * N_ROWS + i]) * (1.0f / 8192.0f);
#pragma unroll
  for (int off = 32; off > 0; off >>= 1) term += __shfl_down(term, off, 64);
  __shared__ float red[4];
  const int lane = threadIdx.x & 63, w = threadIdx.x >> 6;
  if (lane == 0) red[w] = term;
  __syncthreads();
  if (threadIdx.x == 0) atomicAdd(out, red[0] + red[1] + red[2] + red[3]);
}

// ---------------- launcher ----------------
extern "C" void kernel_launch(void* const* d_in, const int* in_sizes, int n_in,
                              void* d_out, int out_size, void* d_ws, size_t ws_size,
                              hipStream_t stream) {
  const float* e1 = (const float*)d_in[0];
  const float* e2 = (const float*)d_in[1];
  char* ws = (char*)d_ws;

  const size_t HBYTES = (size_t)N_ROWS * DFULL * sizeof(half_t);   // 12,582,912
  const size_t IBYTES = (size_t)5 * N_ROWS * sizeof(float);        //    163,840
  half_t* h1      = (half_t*)ws;
  half_t* h2      = (half_t*)(ws + HBYTES);
  float*  inv1    = (float*)(ws + 2 * HBYTES);
  float*  inv2    = (float*)(ws + 2 * HBYTES + IBYTES);
  float*  diag    = (float*)(ws + 2 * HBYTES + 2 * IBYTES);
  float*  partial = (float*)(ws + 2 * HBYTES + 3 * IBYTES);        // 64*5*8192*4 = 10,485,760
  const size_t NEED = 2 * HBYTES + 3 * IBYTES + (size_t)64 * 5 * N_ROWS * sizeof(float);
  if (ws_size < NEED) return;

  hipMemsetAsync(d_out, 0, sizeof(float) * out_size, stream);
  mcl_prep<<<2 * N_ROWS, 256, 0, stream>>>(e1, e2, h1, h2, inv1, inv2);
  mcl_main<<<4096, 512, 0, stream>>>(h1, h2, inv1, inv2, diag, partial);
  mcl_reduce<<<160, 256, 0, stream>>>(partial, diag, (float*)d_out);
}

// Round 4
// 173.820 us; speedup vs baseline: 3.0044x; 3.0044x over previous
//
#include <hip/hip_runtime.h>
#include <hip/hip_fp16.h>
#include <math.h>

typedef _Float16 half_t;
typedef __attribute__((ext_vector_type(8))) _Float16 half8;
typedef __attribute__((ext_vector_type(4))) float f32x4;

#define AS1 __attribute__((address_space(1)))
#define AS3 __attribute__((address_space(3)))

#define N_ROWS 8192
#define DFULL 768
#define LOG2E 1.4426950408889634f
#define KSC (LOG2E / 0.05f)
#define NEGSH (-28.853900817779268f)   // -20 * log2(e)
#define LN2 0.6931471805599453f

__device__ __forceinline__ void gload_lds16(const void* g, void* l) {
  __builtin_amdgcn_global_load_lds((const AS1 void*)g, (AS3 void*)l, 16, 0, 0);
}

// ---------------- kernel 1: per-row prefix norms + fp16 convert ----------------
__global__ __launch_bounds__(256) void mcl_prep(
    const float* __restrict__ e1, const float* __restrict__ e2,
    half_t* __restrict__ h1, half_t* __restrict__ h2,
    float* __restrict__ inv1, float* __restrict__ inv2)
{
  const int b = blockIdx.x;
  const int mat = b >> 13, row = b & (N_ROWS - 1);
  const float* src = (mat ? e2 : e1) + (size_t)row * DFULL;
  half_t* dst = (mat ? h2 : h1) + (size_t)row * DFULL;
  float* invo = mat ? inv2 : inv1;
  const int t = threadIdx.x;

  float p0=0.f,p1=0.f,p2=0.f,p3=0.f,p4=0.f;
#pragma unroll
  for (int j = 0; j < 3; ++j) {
    const int e = t + j * 256;
    const float x = src[e];
    dst[e] = (half_t)x;
    const float xx = x * x;
    p0 += (e < 64)  ? xx : 0.f;
    p1 += (e < 128) ? xx : 0.f;
    p2 += (e < 256) ? xx : 0.f;
    p3 += (e < 512) ? xx : 0.f;
    p4 += xx;
  }
#pragma unroll
  for (int off = 32; off > 0; off >>= 1) {
    p0 += __shfl_down(p0, off, 64);
    p1 += __shfl_down(p1, off, 64);
    p2 += __shfl_down(p2, off, 64);
    p3 += __shfl_down(p3, off, 64);
    p4 += __shfl_down(p4, off, 64);
  }
  __shared__ float red[4][5];
  const int lane = t & 63, w = t >> 6;
  if (lane == 0) { red[w][0]=p0; red[w][1]=p1; red[w][2]=p2; red[w][3]=p3; red[w][4]=p4; }
  __syncthreads();
  if (t == 0) {
#pragma unroll
    for (int s = 0; s < 5; ++s) {
      const float q = red[0][s]+red[1][s]+red[2][s]+red[3][s];
      invo[s * N_ROWS + row] = 1.f / fmaxf(sqrtf(q), 1e-8f);
    }
  }
}

// ---------------- kernel 2: fused cumulative GEMM + checkpoint softmax partials ----------------
// 256 threads = 4 waves (2x2), per-wave 64x64 output. Single-buffered LDS,
// 2-barrier m97-style schedule; low LDS (37 KB) -> 4 blocks/CU so inter-block
// wave overlap hides the staging drain.
// Swapped-operand MFMA: acc[n][m] = mfma(bf[n], af[m], .) ->
//   i (softmax row)  = wr*64 + m*16 + (lane&15)        [lane-low]
//   j (reduce axis)  = wc*64 + n*16 + (lane>>4)*4 + rg [register + lane-hi]
__global__ __launch_bounds__(256, 2) void mcl_main(
    const half_t* __restrict__ h1, const half_t* __restrict__ h2,
    const float* __restrict__ inv1, const float* __restrict__ inv2,
    float* __restrict__ diag, float* __restrict__ partial)
{
  __shared__ __align__(16) half_t sA[128 * 64];
  __shared__ __align__(16) half_t sB[128 * 64];
  __shared__ float rowsumW[2][5][128];   // [wc][dim][row]

  const int tid = threadIdx.x;
  const int lane = tid & 63, wid = tid >> 6;
  const int wr = wid >> 1, wc = wid & 1;
  const int l15 = lane & 15, lh = lane >> 4;

  // XCD-chunked + 8x8-supertile swizzle (bijective: 4096 = 8 * 512)
  const int id = blockIdx.x;
  const int nid = (id & 7) * 512 + (id >> 3);
  const int st = nid >> 6, tt = nid & 63;
  const int bi = ((st >> 3) << 3) + (tt >> 3);
  const int bj = ((st & 7) << 3) + (tt & 7);
  const int rowA0 = bi * 128, rowB0 = bj * 128;

  for (int x = tid; x < 2 * 5 * 128; x += 256) ((float*)rowsumW)[x] = 0.f;

  f32x4 acc[4][4];  // [n][m]
#pragma unroll
  for (int n = 0; n < 4; ++n)
#pragma unroll
    for (int m = 0; m < 4; ++m) acc[n][m] = (f32x4)0.f;

  int dcp = 0;
#pragma unroll 1
  for (int ck = 0; ck < 12; ++ck) {
    const int k0 = ck * 64;
    // ---- stage A,B chunk (linear LDS dest; XOR swizzle pre-applied to global src) ----
#pragma unroll
    for (int r = 0; r < 4; ++r) {
      const int c = ((r * 4 + wid) << 6) + lane;   // 16B-chunk index 0..1023
      const int row = c >> 3, slot = c & 7;
      const int koff = k0 + ((slot ^ (row & 7)) << 3);
      gload_lds16(h1 + (size_t)(rowA0 + row) * DFULL + koff,
                  (char*)sA + ((size_t)(r * 4 + wid) << 10));
      gload_lds16(h2 + (size_t)(rowB0 + row) * DFULL + koff,
                  (char*)sB + ((size_t)(r * 4 + wid) << 10));
    }
    __syncthreads();
    // ---- 2 MFMA K-steps of 32 ----
#pragma unroll
    for (int ks = 0; ks < 2; ++ks) {
      half8 af[4], bf[4];
#pragma unroll
      for (int m = 0; m < 4; ++m) {
        const int rowa = wr * 64 + m * 16 + l15;
        const int slota = (ks * 4 + lh) ^ (rowa & 7);
        af[m] = *(const half8*)((const char*)sA + rowa * 128 + (slota << 4));
        const int rowb = wc * 64 + m * 16 + l15;
        const int slotb = (ks * 4 + lh) ^ (rowb & 7);
        bf[m] = *(const half8*)((const char*)sB + rowb * 128 + (slotb << 4));
      }
#pragma unroll
      for (int n = 0; n < 4; ++n)
#pragma unroll
        for (int m = 0; m < 4; ++m)
          acc[n][m] = __builtin_amdgcn_mfma_f32_16x16x32_f16(bf[n], af[m], acc[n][m], 0, 0, 0);
    }
    // ---- checkpoint epilogue (cumulative K = 64,128,256,512,768) ----
    if (ck == 0 || ck == 1 || ck == 3 || ck == 7 || ck == 11) {
      // scales straight from global (160 KB tables, L1/L2-hot)
      float s1K[4];
#pragma unroll
      for (int m = 0; m < 4; ++m)
        s1K[m] = inv1[dcp * N_ROWS + rowA0 + wr * 64 + m * 16 + l15] * KSC;
      f32x4 s2v[4];
#pragma unroll
      for (int n = 0; n < 4; ++n)
        s2v[n] = *(const f32x4*)(inv2 + dcp * N_ROWS + rowB0 + wc * 64 + n * 16 + (lh << 2));

      float rp[4] = {0.f, 0.f, 0.f, 0.f};
#pragma unroll
      for (int n = 0; n < 4; ++n)
#pragma unroll
        for (int m = 0; m < 4; ++m)
#pragma unroll
          for (int rg = 0; rg < 4; ++rg)
            rp[m] += __builtin_amdgcn_exp2f(fmaf(acc[n][m][rg] * s2v[n][rg], s1K[m], NEGSH));

      // reduce over lane-hi (j sub-axis)
#pragma unroll
      for (int m = 0; m < 4; ++m) {
        rp[m] += __shfl_xor(rp[m], 16, 64);
        rp[m] += __shfl_xor(rp[m], 32, 64);
      }
      if (lh == 0) {
#pragma unroll
        for (int m = 0; m < 4; ++m)
          rowsumW[wc][dcp][wr * 64 + m * 16 + l15] += rp[m];
      }
      // diagonal logits: i==j needs n==m and lh*4+rg==l15
      if (bi == bj && wr == wc && lh == (l15 >> 2)) {
        const int rgd = l15 & 3;
#pragma unroll
        for (int m = 0; m < 4; ++m) {
          const float lg = acc[m][m][rgd] * s1K[m] * s2v[m][rgd] * LN2;
          diag[dcp * N_ROWS + rowA0 + wr * 64 + m * 16 + l15] = lg;
        }
      }
      ++dcp;
    }
    __syncthreads();
  }

  // write per-(column-block) partial sumexp
  for (int x = tid; x < 5 * 128; x += 256) {
    const int d = x >> 7, r = x & 127;
    partial[((size_t)bj * 5 + d) * N_ROWS + rowA0 + r] = rowsumW[0][d][r] + rowsumW[1][d][r];
  }
}

// ---------------- kernel 3: final reduction ----------------
__global__ __launch_bounds__(256) void mcl_reduce(
    const float* __restrict__ partial, const float* __restrict__ diag,
    float* __restrict__ out)
{
  const int item = blockIdx.x * 256 + threadIdx.x;  // 0..40959
  const int d = item >> 13;
  const int i = item & (N_ROWS - 1);
  float s = 0.f;
#pragma unroll 4
  for (int bj = 0; bj < 64; ++bj)
    s += partial[((size_t)bj * 5 + d) * N_ROWS + i];
  float term = (20.0f + logf(s) - diag[d * N_ROWS + i]) * (1.0f / 8192.0f);
#pragma unroll
  for (int off = 32; off > 0; off >>= 1) term += __shfl_down(term, off, 64);
  __shared__ float red[4];
  const int lane = threadIdx.x & 63, w = threadIdx.x >> 6;
  if (lane == 0) red[w] = term;
  __syncthreads();
  if (threadIdx.x == 0) atomicAdd(out, red[0] + red[1] + red[2] + red[3]);
}

// ---------------- launcher ----------------
extern "C" void kernel_launch(void* const* d_in, const int* in_sizes, int n_in,
                              void* d_out, int out_size, void* d_ws, size_t ws_size,
                              hipStream_t stream) {
  const float* e1 = (const float*)d_in[0];
  const float* e2 = (const float*)d_in[1];
  char* ws = (char*)d_ws;

  const size_t HBYTES = (size_t)N_ROWS * DFULL * sizeof(half_t);   // 12,582,912
  const size_t IBYTES = (size_t)5 * N_ROWS * sizeof(float);        //    163,840
  half_t* h1      = (half_t*)ws;
  half_t* h2      = (half_t*)(ws + HBYTES);
  float*  inv1    = (float*)(ws + 2 * HBYTES);
  float*  inv2    = (float*)(ws + 2 * HBYTES + IBYTES);
  float*  diag    = (float*)(ws + 2 * HBYTES + 2 * IBYTES);
  float*  partial = (float*)(ws + 2 * HBYTES + 3 * IBYTES);        // 64*5*8192*4 = 10,485,760
  const size_t NEED = 2 * HBYTES + 3 * IBYTES + (size_t)64 * 5 * N_ROWS * sizeof(float);
  if (ws_size < NEED) return;

  hipMemsetAsync(d_out, 0, sizeof(float) * out_size, stream);
  mcl_prep<<<2 * N_ROWS, 256, 0, stream>>>(e1, e2, h1, h2, inv1, inv2);
  mcl_main<<<4096, 256, 0, stream>>>(h1, h2, inv1, inv2, diag, partial);
  mcl_reduce<<<160, 256, 0, stream>>>(partial, diag, (float*)d_out);
}